// Round 14
// baseline (110.413 us; speedup 1.0000x reference)
//
#include <hip/hip_runtime.h>
#include <hip/hip_bf16.h>

#define B_DIM 64
#define H_DIM 256
#define NCHG 8            // t-groups (grid y) -> 512 blocks = 2/CU
#define CHUNKS 4          // chunks per block
#define TCH 64            // t-rows per chunk

typedef __attribute__((ext_vector_type(8))) short short8;
typedef __attribute__((ext_vector_type(4))) float f32x4;

__device__ __forceinline__ unsigned short bfbits(float f) {
    __hip_bfloat16 h = __float2bfloat16(f);
    unsigned short u;
    __builtin_memcpy(&u, &h, 2);
    return u;
}
__device__ __forceinline__ float fexp(float x) {
    float r;
    asm("v_exp_f32 %0, %1" : "=v"(r) : "v"(x * 1.4426950408889634f));
    return r;
}
__device__ __forceinline__ float ftanh(float x) {
    float e, r;
    asm("v_exp_f32 %0, %1" : "=v"(e) : "v"(x * 2.8853900817779268f));
    asm("v_rcp_f32 %0, %1" : "=v"(r) : "v"(e + 1.0f));
    return 1.0f - 2.0f * r;
}
__device__ __forceinline__ float fsigmoid(float x) {
    float e, r;
    asm("v_exp_f32 %0, %1" : "=v"(e) : "v"(x * -1.4426950408889634f));
    asm("v_rcp_f32 %0, %1" : "=v"(r) : "v"(e + 1.0f));
    return r;
}
// raw barrier: LDS visibility only — in-flight global loads survive (no vmcnt drain)
__device__ __forceinline__ void lds_barrier() {
    asm volatile("s_waitcnt lgkmcnt(0)" ::: "memory");
    __builtin_amdgcn_s_barrier();
    __builtin_amdgcn_sched_barrier(0);
}

// K0: fused WmT prep (blocks 0..255) + qs GEMV (blocks 256..319)
__global__ void prep_qs_kernel(const float* __restrict__ W_a1,
                               const float* __restrict__ input,
                               const float* __restrict__ state,
                               unsigned short* __restrict__ WmT,
                               float* __restrict__ qs) {
    __shared__ float cat[512];
    int bid = blockIdx.x, tid = threadIdx.x;
    if (bid < 256) {
        WmT[tid * 256 + bid] = bfbits(W_a1[(512 + bid) * 256 + tid]);
    } else {
        int b = bid - 256;
        cat[tid] = input[b * 256 + tid];
        cat[256 + tid] = state[b * 256 + tid];
        __syncthreads();
        int a = tid;
        float s0 = 0.f, s1 = 0.f, s2 = 0.f, s3 = 0.f;
        #pragma unroll 4
        for (int k = 0; k < 512; k += 4) {
            s0 += cat[k]     * W_a1[(k)     * 256 + a];
            s1 += cat[k + 1] * W_a1[(k + 1) * 256 + a];
            s2 += cat[k + 2] * W_a1[(k + 2) * 256 + a];
            s3 += cat[k + 3] * W_a1[(k + 3) * 256 + a];
        }
        qs[b * 256 + a] = (s0 + s1) + (s2 + s3);
    }
}

// K1: unchanged from R13 (best measured attn structure).
__global__ __launch_bounds__(512, 2) void attn_kernel(
    const float* __restrict__ memory, const int* __restrict__ mask,
    const unsigned short* __restrict__ WmT,
    const float* __restrict__ qs, const float* __restrict__ w_a2,
    float* __restrict__ part_l, float* __restrict__ part_acc)
{
    extern __shared__ char smem[];
    unsigned short* slab0 = (unsigned short*)smem;            // [64][256] bf16, swizzled
    unsigned short* slab1 = (unsigned short*)(smem + 32768);
    float* lpart = (float*)(smem + 65536);                    // [8][64]
    int*   maskL = (int*)(smem + 65536 + 2048);               // [256]

    int b = blockIdx.x, g = blockIdx.y;
    int tid = threadIdx.x;
    int lane = tid & 63, w = tid >> 6;
    int lr = lane & 15, lh = lane >> 4;
    int tbase = g * (CHUNKS * TCH);
    const float* mbase = memory + (size_t)tbase * (B_DIM * H_DIM) + b * H_DIM;

    int wa0 = w * 32;
    short8 areg[8][2];                            // 64 persistent VGPRs
    #pragma unroll
    for (int kk = 0; kk < 8; ++kk)
        #pragma unroll
        for (int mf = 0; mf < 2; ++mf)
            areg[kk][mf] = *(const short8*)(WmT + (wa0 + mf * 16 + lr) * 256 + kk * 32 + lh * 8);

    float qv[2][4], wv[2][4];
    #pragma unroll
    for (int mf = 0; mf < 2; ++mf)
        #pragma unroll
        for (int r = 0; r < 4; ++r) {
            int a = wa0 + mf * 16 + lh * 4 + r;
            qv[mf][r] = qs[b * 256 + a];
            wv[mf][r] = w_a2[a];
        }

    if (tid < CHUNKS * TCH) maskL[tid] = mask[(tbase + tid) * B_DIM + b];

    int wby = (lane * 8) ^ (w << 4);              // swizzled byte off (row&7 == w)

    float4 ld[8];
#define ISSUE(q)                                                               \
    _Pragma("unroll") for (int i = 0; i < 8; ++i)                              \
        ld[i] = *((const float4*)(mbase + (size_t)((q) * TCH + i * 8 + w) *    \
                                  (B_DIM * H_DIM)) + lane);
#define WRITE(sl)                                                              \
    _Pragma("unroll") for (int i = 0; i < 8; ++i) {                            \
        ushort4 o;                                                             \
        o.x = bfbits(ld[i].x); o.y = bfbits(ld[i].y);                          \
        o.z = bfbits(ld[i].z); o.w = bfbits(ld[i].w);                          \
        *(ushort4*)((char*)(sl) + (i * 8 + w) * 512 + wby) = o;                \
    }

    ISSUE(0)
    WRITE(slab0)

    float a8[8] = {0.f, 0.f, 0.f, 0.f, 0.f, 0.f, 0.f, 0.f};
    float l_acc = 0.f;
    int slice4 = ((lane >> 5) + 2 * w) * 4;       // PV t-base
    int hpvb = (lane & 31) * 16;                  // PV h byte-base

    for (int s = 0; s < CHUNKS; ++s) {
        const char* cur = (const char*)((s & 1) ? slab1 : slab0);
        char* nxt = (char*)((s & 1) ? slab0 : slab1);

        lds_barrier();                            // top: slab writes visible

        if (s + 1 < CHUNKS) { ISSUE(s + 1) }

        f32x4 acc[2][4];
        #pragma unroll
        for (int mf = 0; mf < 2; ++mf)
            #pragma unroll
            for (int nf = 0; nf < 4; ++nf)
                acc[mf][nf] = (f32x4){0.f, 0.f, 0.f, 0.f};
        #pragma unroll
        for (int kk = 0; kk < 8; ++kk) {
            int kbyte = kk * 64 + lh * 16;
            #pragma unroll
            for (int nf = 0; nf < 4; ++nf) {
                int t = nf * 16 + lr;
                int sw = kbyte ^ ((t & 7) << 4);
                short8 bfr = *(const short8*)(cur + t * 512 + sw);
                acc[0][nf] = __builtin_amdgcn_mfma_f32_16x16x32_bf16(areg[kk][0], bfr, acc[0][nf], 0, 0, 0);
                acc[1][nf] = __builtin_amdgcn_mfma_f32_16x16x32_bf16(areg[kk][1], bfr, acc[1][nf], 0, 0, 0);
            }
        }

        #pragma unroll
        for (int nf = 0; nf < 4; ++nf) {
            float sv = 0.f;
            #pragma unroll
            for (int mf = 0; mf < 2; ++mf)
                #pragma unroll
                for (int r = 0; r < 4; ++r)
                    sv += wv[mf][r] * ftanh(qv[mf][r] + acc[mf][nf][r]);
            sv += __shfl_xor(sv, 16);
            sv += __shfl_xor(sv, 32);
            if (lh == 0) lpart[w * 64 + nf * 16 + lr] = sv;
        }
        lds_barrier();                            // A: lpart visible

        float lg = 0.f;
        #pragma unroll
        for (int ww = 0; ww < 8; ++ww) lg += lpart[ww * 64 + lane];
        float pself = maskL[s * 64 + lane] ? fexp(lg) : 0.f;
        if (w == 0) l_acc += pself;

        #pragma unroll
        for (int tt = 0; tt < 4; ++tt) {
            int tl = slice4 + tt;
            float pt = __shfl(pself, tl);         // tl in [8w, 8w+8) -> same wave
            int swb = hpvb ^ ((tl & 7) << 4);
            uint4 u = *(const uint4*)(cur + tl * 512 + swb);
            a8[0] += pt * __uint_as_float(u.x << 16);
            a8[1] += pt * __uint_as_float(u.x & 0xFFFF0000u);
            a8[2] += pt * __uint_as_float(u.y << 16);
            a8[3] += pt * __uint_as_float(u.y & 0xFFFF0000u);
            a8[4] += pt * __uint_as_float(u.z << 16);
            a8[5] += pt * __uint_as_float(u.z & 0xFFFF0000u);
            a8[6] += pt * __uint_as_float(u.w << 16);
            a8[7] += pt * __uint_as_float(u.w & 0xFFFF0000u);
        }

        if (s + 1 < CHUNKS) { WRITE(nxt) }
    }
#undef ISSUE
#undef WRITE

    __syncthreads();
    float* acc2 = (float*)smem;                   // [16][256]
    int oct = lane & 31, slice = 2 * w + (lane >> 5), h0 = oct * 8;
    *(float4*)(&acc2[slice * 256 + h0])     = (float4){a8[0], a8[1], a8[2], a8[3]};
    *(float4*)(&acc2[slice * 256 + h0 + 4]) = (float4){a8[4], a8[5], a8[6], a8[7]};
    __syncthreads();
    int pidx = g * B_DIM + b;
    if (tid < 256) {
        float ssum = 0.f;
        #pragma unroll
        for (int sl = 0; sl < 16; ++sl) ssum += acc2[sl * 256 + tid];
        part_acc[(size_t)pidx * 256 + tid] = ssum;
    }
    if (w == 0) {
        #pragma unroll
        for (int d = 1; d < 64; d <<= 1) l_acc += __shfl_xor(l_acc, d);
        if (lane == 0) part_l[pidx] = l_acc;
    }
}

// K2: fused merge + gate + GRU, one kernel per b (64 blocks x 512 threads).
// Phase 1: merge partials -> attn row; gate GEMV -> gL in LDS.
// Phase 2: GRU GEMVs via 16-lane groups (coalesced W rows, L2-resident).
// Phase 3: gate combine -> out.
__global__ __launch_bounds__(512) void tail_kernel(
    const float* __restrict__ part_l, const float* __restrict__ part_acc,
    const float* __restrict__ input,  const float* __restrict__ state,
    const float* __restrict__ W_gate,
    const float* __restrict__ W_ih,   const float* __restrict__ W_hh,
    const float* __restrict__ b_ih,   const float* __restrict__ b_hh,
    float* __restrict__ out) {
    __shared__ float ni[512];
    __shared__ float gL[512];
    __shared__ float st[256];
    __shared__ float xi[768];
    __shared__ float xh[768];
    int b = blockIdx.x, tid = threadIdx.x;

    // ---- phase 1a: inputs + merge ----
    if (tid >= 256) {
        int k = tid - 256;
        ni[k] = input[b * 256 + k];
        st[k] = state[b * 256 + k];
    } else {
        int h = tid;
        float L = 0.f, s = 0.f;
        #pragma unroll
        for (int c = 0; c < NCHG; ++c) {
            L += part_l[c * 64 + b];
            s += part_acc[(size_t)(c * 64 + b) * 256 + h];
        }
        ni[256 + h] = s / L;
    }
    __syncthreads();

    // ---- phase 1b: gate GEMV (thread = output j) ----
    {
        int j = tid;
        float s0 = 0.f, s1 = 0.f, s2 = 0.f, s3 = 0.f;
        #pragma unroll 4
        for (int k = 0; k < 512; k += 4) {
            s0 += ni[k]     * W_gate[(k)     * 512 + j];
            s1 += ni[k + 1] * W_gate[(k + 1) * 512 + j];
            s2 += ni[k + 2] * W_gate[(k + 2) * 512 + j];
            s3 += ni[k + 3] * W_gate[(k + 3) * 512 + j];
        }
        float s = (s0 + s1) + (s2 + s3);
        gL[j] = ni[j] * fsigmoid(s);
    }
    __syncthreads();

    // ---- phase 2: GRU GEMVs. 32 groups x 16 lanes; group does 24 j's ----
    {
        int grp = tid >> 4, lk = tid & 15;
        const float4* gp = (const float4*)(&gL[0]);
        const float4* sp = (const float4*)(&st[0]);
        for (int m = 0; m < 24; ++m) {
            int j = grp + 32 * m;                 // consecutive groups -> consecutive rows
            float si = 0.f;
            const float4* wi = (const float4*)(W_ih + (size_t)j * 512);
            #pragma unroll
            for (int it = 0; it < 8; ++it) {
                float4 wvv = wi[it * 16 + lk];
                float4 gv = gp[it * 16 + lk];
                si += wvv.x * gv.x + wvv.y * gv.y + wvv.z * gv.z + wvv.w * gv.w;
            }
            float sh = 0.f;
            const float4* wh = (const float4*)(W_hh + (size_t)j * 256);
            #pragma unroll
            for (int it = 0; it < 4; ++it) {
                float4 wvv = wh[it * 16 + lk];
                float4 sv = sp[it * 16 + lk];
                sh += wvv.x * sv.x + wvv.y * sv.y + wvv.z * sv.z + wvv.w * sv.w;
            }
            #pragma unroll
            for (int d = 1; d < 16; d <<= 1) {
                si += __shfl_xor(si, d);
                sh += __shfl_xor(sh, d);
            }
            if (lk == 0) {
                xi[j] = si + b_ih[j];
                xh[j] = sh + b_hh[j];
            }
        }
    }
    __syncthreads();

    // ---- phase 3: gate combine ----
    if (tid < 256) {
        int h = tid;
        float r = fsigmoid(xi[h]       + xh[h]);
        float z = fsigmoid(xi[256 + h] + xh[256 + h]);
        float n = ftanh(xi[512 + h] + r * xh[512 + h]);
        out[b * 256 + h] = (1.f - z) * n + z * st[h];
    }
}

extern "C" void kernel_launch(void* const* d_in, const int* in_sizes, int n_in,
                              void* d_out, int out_size, void* d_ws, size_t ws_size,
                              hipStream_t stream) {
    const float* input  = (const float*)d_in[0];
    const float* memory = (const float*)d_in[1];
    const int*   mask   = (const int*)d_in[2];
    const float* state  = (const float*)d_in[3];
    const float* W_a1   = (const float*)d_in[4];
    const float* w_a2   = (const float*)d_in[5];
    const float* W_gate = (const float*)d_in[6];
    const float* W_ih   = (const float*)d_in[7];
    const float* W_hh   = (const float*)d_in[8];
    const float* b_ih   = (const float*)d_in[9];
    const float* b_hh   = (const float*)d_in[10];
    float* out = (float*)d_out;

    char* ws = (char*)d_ws;
    unsigned short* WmT = (unsigned short*)(ws + 0);        // 131072 B
    float* qs       = (float*)(ws + 131072);                // 65536 B
    float* part_l   = (float*)(ws + 327680);                // 2048 B   [g][b]
    float* part_acc = (float*)(ws + 335872);                // 524288 B [g][b][h]

    prep_qs_kernel<<<320, 256, 0, stream>>>(W_a1, input, state, WmT, qs);

    (void)hipFuncSetAttribute((const void*)attn_kernel,
                              hipFuncAttributeMaxDynamicSharedMemorySize, 68608);
    attn_kernel<<<dim3(B_DIM, NCHG), 512, 68608, stream>>>(
        memory, mask, WmT, qs, w_a2, part_l, part_acc);

    tail_kernel<<<64, 512, 0, stream>>>(part_l, part_acc, input, state,
                                        W_gate, W_ih, W_hh, b_ih, b_hh, out);
}

// Round 15
// 79.096 us; speedup vs baseline: 1.3959x; 1.3959x over previous
//
#include <hip/hip_runtime.h>
#include <hip/hip_bf16.h>

#define B_DIM 64
#define H_DIM 256
#define NCHG 8            // t-groups (grid y) -> 512 blocks = 2/CU
#define CHUNKS 4          // chunks per block
#define TCH 64            // t-rows per chunk

typedef __attribute__((ext_vector_type(8))) short short8;
typedef __attribute__((ext_vector_type(4))) float f32x4;

__device__ __forceinline__ unsigned short bfbits(float f) {
    __hip_bfloat16 h = __float2bfloat16(f);
    unsigned short u;
    __builtin_memcpy(&u, &h, 2);
    return u;
}
__device__ __forceinline__ float fexp(float x) {
    float r;
    asm("v_exp_f32 %0, %1" : "=v"(r) : "v"(x * 1.4426950408889634f));
    return r;
}
__device__ __forceinline__ float ftanh(float x) {
    float e, r;
    asm("v_exp_f32 %0, %1" : "=v"(e) : "v"(x * 2.8853900817779268f));
    asm("v_rcp_f32 %0, %1" : "=v"(r) : "v"(e + 1.0f));
    return 1.0f - 2.0f * r;
}
__device__ __forceinline__ float fsigmoid(float x) {
    float e, r;
    asm("v_exp_f32 %0, %1" : "=v"(e) : "v"(x * -1.4426950408889634f));
    asm("v_rcp_f32 %0, %1" : "=v"(r) : "v"(e + 1.0f));
    return r;
}
// raw barrier: LDS visibility only — in-flight global loads survive (no vmcnt drain)
__device__ __forceinline__ void lds_barrier() {
    asm volatile("s_waitcnt lgkmcnt(0)" ::: "memory");
    __builtin_amdgcn_s_barrier();
    __builtin_amdgcn_sched_barrier(0);
}

// K0: fused WmT prep (blocks 0..255) + qs GEMV (blocks 256..319)
__global__ void prep_qs_kernel(const float* __restrict__ W_a1,
                               const float* __restrict__ input,
                               const float* __restrict__ state,
                               unsigned short* __restrict__ WmT,
                               float* __restrict__ qs) {
    __shared__ float cat[512];
    int bid = blockIdx.x, tid = threadIdx.x;
    if (bid < 256) {
        WmT[tid * 256 + bid] = bfbits(W_a1[(512 + bid) * 256 + tid]);
    } else {
        int b = bid - 256;
        cat[tid] = input[b * 256 + tid];
        cat[256 + tid] = state[b * 256 + tid];
        __syncthreads();
        int a = tid;
        float s0 = 0.f, s1 = 0.f, s2 = 0.f, s3 = 0.f;
        #pragma unroll 4
        for (int k = 0; k < 512; k += 4) {
            s0 += cat[k]     * W_a1[(k)     * 256 + a];
            s1 += cat[k + 1] * W_a1[(k + 1) * 256 + a];
            s2 += cat[k + 2] * W_a1[(k + 2) * 256 + a];
            s3 += cat[k + 3] * W_a1[(k + 3) * 256 + a];
        }
        qs[b * 256 + a] = (s0 + s1) + (s2 + s3);
    }
}

// K1: R13 datapath, 1 barrier/chunk. Wave w stages AND PV-reads rows
// [8w, 8w+8) (wave-own), so the only cross-wave handoffs (slab for MFMA,
// lpart for softmax) share a single raw barrier. lpart ping-pongs by s&1.
__global__ __launch_bounds__(512, 2) void attn_kernel(
    const float* __restrict__ memory, const int* __restrict__ mask,
    const unsigned short* __restrict__ WmT,
    const float* __restrict__ qs, const float* __restrict__ w_a2,
    float* __restrict__ part_l, float* __restrict__ part_acc)
{
    extern __shared__ char smem[];
    unsigned short* slab0 = (unsigned short*)smem;            // [64][256] bf16, swizzled
    unsigned short* slab1 = (unsigned short*)(smem + 32768);
    float* lpart = (float*)(smem + 65536);                    // [2][8][64] ping-pong
    int*   maskL = (int*)(smem + 65536 + 4096);               // [256]

    int b = blockIdx.x, g = blockIdx.y;
    int tid = threadIdx.x;
    int lane = tid & 63, w = tid >> 6;
    int lr = lane & 15, lh = lane >> 4;
    int tbase = g * (CHUNKS * TCH);
    const float* mbase = memory + (size_t)tbase * (B_DIM * H_DIM) + b * H_DIM;

    int wa0 = w * 32;
    short8 areg[8][2];                            // 64 persistent VGPRs
    #pragma unroll
    for (int kk = 0; kk < 8; ++kk)
        #pragma unroll
        for (int mf = 0; mf < 2; ++mf)
            areg[kk][mf] = *(const short8*)(WmT + (wa0 + mf * 16 + lr) * 256 + kk * 32 + lh * 8);

    float qv[2][4], wv[2][4];
    #pragma unroll
    for (int mf = 0; mf < 2; ++mf)
        #pragma unroll
        for (int r = 0; r < 4; ++r) {
            int a = wa0 + mf * 16 + lh * 4 + r;
            qv[mf][r] = qs[b * 256 + a];
            wv[mf][r] = w_a2[a];
        }

    if (tid < CHUNKS * TCH) maskL[tid] = mask[(tbase + tid) * B_DIM + b];

    float4 ld[8];
    // wave w owns rows [8w, 8w+8); lane covers the 64 float4 columns of a row
#define ISSUE(q)                                                               \
    _Pragma("unroll") for (int i = 0; i < 8; ++i)                              \
        ld[i] = *((const float4*)(mbase + (size_t)((q) * TCH + 8 * w + i) *    \
                                  (B_DIM * H_DIM)) + lane);
#define WRITE(sl)                                                              \
    _Pragma("unroll") for (int i = 0; i < 8; ++i) {                            \
        ushort4 o;                                                             \
        o.x = bfbits(ld[i].x); o.y = bfbits(ld[i].y);                          \
        o.z = bfbits(ld[i].z); o.w = bfbits(ld[i].w);                          \
        *(ushort4*)((char*)(sl) + (8 * w + i) * 512 + ((lane * 8) ^ (i << 4))) = o; \
    }

    // prologue: chunk 0 -> slab0; issue chunk 1
    ISSUE(0)
    WRITE(slab0)
    ISSUE(1)
    lds_barrier();

    float a8[8] = {0.f, 0.f, 0.f, 0.f, 0.f, 0.f, 0.f, 0.f};
    float l_acc = 0.f;
    int slice4 = ((lane >> 5) + 2 * w) * 4;       // PV t-base: rows [8w, 8w+8)
    int hpvb = (lane & 31) * 16;                  // PV h byte-base

    for (int s = 0; s < CHUNKS; ++s) {
        const char* cur = (const char*)((s & 1) ? slab1 : slab0);
        char* nxt = (char*)((s & 1) ? slab0 : slab1);
        float* lp = lpart + (s & 1) * 512;

        // 2. MFMA(s): cross-wave reads of slab[cur] (writers fenced by barrier(s-1))
        f32x4 acc[2][4];
        #pragma unroll
        for (int mf = 0; mf < 2; ++mf)
            #pragma unroll
            for (int nf = 0; nf < 4; ++nf)
                acc[mf][nf] = (f32x4){0.f, 0.f, 0.f, 0.f};
        #pragma unroll
        for (int kk = 0; kk < 8; ++kk) {
            int kbyte = kk * 64 + lh * 16;
            #pragma unroll
            for (int nf = 0; nf < 4; ++nf) {
                int t = nf * 16 + lr;
                int sw = kbyte ^ ((t & 7) << 4);
                short8 bfr = *(const short8*)(cur + t * 512 + sw);
                acc[0][nf] = __builtin_amdgcn_mfma_f32_16x16x32_bf16(areg[kk][0], bfr, acc[0][nf], 0, 0, 0);
                acc[1][nf] = __builtin_amdgcn_mfma_f32_16x16x32_bf16(areg[kk][1], bfr, acc[1][nf], 0, 0, 0);
            }
        }

        // 3. epilogue -> lpart[s&1]
        #pragma unroll
        for (int nf = 0; nf < 4; ++nf) {
            float sv = 0.f;
            #pragma unroll
            for (int mf = 0; mf < 2; ++mf)
                #pragma unroll
                for (int r = 0; r < 4; ++r)
                    sv += wv[mf][r] * ftanh(qv[mf][r] + acc[mf][nf][r]);
            sv += __shfl_xor(sv, 16);
            sv += __shfl_xor(sv, 32);
            if (lh == 0) lp[w * 64 + nf * 16 + lr] = sv;
        }

        // 4. stage chunk s+1 into idle slab (wave-own rows; its last foreign
        //    reader was MFMA(s-1), fenced by barrier(s-1); PV(s-1) read it
        //    wave-own -> program order). Counted vmcnt for ld lands here.
        if (s + 1 < CHUNKS) { WRITE(nxt) }

        // 5. the single barrier: publishes lpart(s) + slab(s+1)
        lds_barrier();

        // 6. softmax: no max-tracking (|logit| <= ||w_a2||_1 ~ 13, f32-safe)
        float lg = 0.f;
        #pragma unroll
        for (int ww = 0; ww < 8; ++ww) lg += lp[ww * 64 + lane];
        float pself = maskL[s * 64 + lane] ? fexp(lg) : 0.f;
        if (w == 0) l_acc += pself;

        // 7. PV from slab[cur], wave-own rows [8w, 8w+8); p via in-wave shuffle
        #pragma unroll
        for (int tt = 0; tt < 4; ++tt) {
            int tl = slice4 + tt;
            float pt = __shfl(pself, tl);
            int swb = hpvb ^ ((tl & 7) << 4);
            uint4 u = *(const uint4*)(cur + tl * 512 + swb);
            a8[0] += pt * __uint_as_float(u.x << 16);
            a8[1] += pt * __uint_as_float(u.x & 0xFFFF0000u);
            a8[2] += pt * __uint_as_float(u.y << 16);
            a8[3] += pt * __uint_as_float(u.y & 0xFFFF0000u);
            a8[4] += pt * __uint_as_float(u.z << 16);
            a8[5] += pt * __uint_as_float(u.z & 0xFFFF0000u);
            a8[6] += pt * __uint_as_float(u.w << 16);
            a8[7] += pt * __uint_as_float(u.w & 0xFFFF0000u);
        }

        // 8. issue loads for chunk s+2 (consumed at step 4 of next iter;
        //    in flight across barrier + MFMA + epilogue)
        if (s + 2 < CHUNKS) { ISSUE(s + 2) }
    }
#undef ISSUE
#undef WRITE

    // ---- final combine: alias acc2 over slab0 (dead) ----
    __syncthreads();
    float* acc2 = (float*)smem;                   // [16][256]
    int oct = lane & 31, slice = 2 * w + (lane >> 5), h0 = oct * 8;
    *(float4*)(&acc2[slice * 256 + h0])     = (float4){a8[0], a8[1], a8[2], a8[3]};
    *(float4*)(&acc2[slice * 256 + h0 + 4]) = (float4){a8[4], a8[5], a8[6], a8[7]};
    __syncthreads();
    int pidx = g * B_DIM + b;
    if (tid < 256) {
        float ssum = 0.f;
        #pragma unroll
        for (int sl = 0; sl < 16; ++sl) ssum += acc2[sl * 256 + tid];
        part_acc[(size_t)pidx * 256 + tid] = ssum;
    }
    if (w == 0) {
        #pragma unroll
        for (int d = 1; d < 64; d <<= 1) l_acc += __shfl_xor(l_acc, d);
        if (lane == 0) part_l[pidx] = l_acc;
    }
}

// K2: fused merge (plain sums over 8 groups) + gate GEMV. block = one b.
__global__ void mergegate_kernel(const float* __restrict__ part_l,
                                 const float* __restrict__ part_acc,
                                 const float* __restrict__ input,
                                 const float* __restrict__ W_gate,
                                 float* __restrict__ gated) {
    __shared__ float ni[512];
    int b = blockIdx.x, tid = threadIdx.x;
    if (tid >= 256) {
        int k = tid - 256;
        ni[k] = input[b * 256 + k];
    } else {
        int h = tid;
        float L = 0.f, s = 0.f;
        #pragma unroll
        for (int c = 0; c < NCHG; ++c) {
            L += part_l[c * 64 + b];
            s += part_acc[(size_t)(c * 64 + b) * 256 + h];
        }
        ni[256 + h] = s / L;
    }
    __syncthreads();
    int j = tid;
    float s0 = 0.f, s1 = 0.f, s2 = 0.f, s3 = 0.f;
    #pragma unroll 4
    for (int k = 0; k < 512; k += 4) {
        s0 += ni[k]     * W_gate[(k)     * 512 + j];
        s1 += ni[k + 1] * W_gate[(k + 1) * 512 + j];
        s2 += ni[k + 2] * W_gate[(k + 2) * 512 + j];
        s3 += ni[k + 3] * W_gate[(k + 3) * 512 + j];
    }
    float s = (s0 + s1) + (s2 + s3);
    gated[b * 512 + j] = ni[j] * fsigmoid(s);
}

// K3: GRU cell. grid 256 = (16 b-tiles x 16 h-tiles), block 768.
__global__ __launch_bounds__(768) void gru_kernel(
    const float* __restrict__ gated, const float* __restrict__ state,
    const float* __restrict__ W_ih, const float* __restrict__ W_hh,
    const float* __restrict__ b_ih, const float* __restrict__ b_hh,
    float* __restrict__ out) {
    __shared__ float ld_g[4][512];
    __shared__ float ld_s[4][256];
    __shared__ float xi[3][16][4];
    __shared__ float xh[3][16][4];
    int ht = blockIdx.x & 15, bt = blockIdx.x >> 4;
    int tid = threadIdx.x;
    #pragma unroll
    for (int i = 0; i < 3; ++i) {
        int idx = i * 768 + tid;
        if (idx < 2048) ld_g[idx >> 9][idx & 511] = gated[(bt * 4 + (idx >> 9)) * 512 + (idx & 511)];
    }
    #pragma unroll
    for (int i = 0; i < 2; ++i) {
        int idx = i * 768 + tid;
        if (idx < 1024) ld_s[idx >> 8][idx & 255] = state[(bt * 4 + (idx >> 8)) * 256 + (idx & 255)];
    }

    int gid = tid >> 4, lk = tid & 15;
    int gate = gid >> 4, hl = gid & 15;
    int j = gate * 256 + ht * 16 + hl;

    float4 wi[8], wh[4];
    #pragma unroll
    for (int it = 0; it < 8; ++it)
        wi[it] = *(const float4*)(W_ih + (size_t)j * 512 + it * 64 + lk * 4);
    #pragma unroll
    for (int it = 0; it < 4; ++it)
        wh[it] = *(const float4*)(W_hh + (size_t)j * 256 + it * 64 + lk * 4);
    float bi = b_ih[j], bh = b_hh[j];
    __syncthreads();

    #pragma unroll
    for (int bb = 0; bb < 4; ++bb) {
        float g0 = 0.f, g1 = 0.f;
        #pragma unroll
        for (int it = 0; it < 8; ++it) {
            float4 gv = *(const float4*)(&ld_g[bb][it * 64 + lk * 4]);
            g0 += wi[it].x * gv.x + wi[it].z * gv.z;
            g1 += wi[it].y * gv.y + wi[it].w * gv.w;
        }
        float h0 = 0.f, h1 = 0.f;
        #pragma unroll
        for (int it = 0; it < 4; ++it) {
            float4 sv = *(const float4*)(&ld_s[bb][it * 64 + lk * 4]);
            h0 += wh[it].x * sv.x + wh[it].z * sv.z;
            h1 += wh[it].y * sv.y + wh[it].w * sv.w;
        }
        float gi_ = g0 + g1, gh_ = h0 + h1;
        #pragma unroll
        for (int m = 1; m < 16; m <<= 1) {
            gi_ += __shfl_xor(gi_, m);
            gh_ += __shfl_xor(gh_, m);
        }
        if (lk == 0) { xi[gate][hl][bb] = gi_ + bi; xh[gate][hl][bb] = gh_ + bh; }
    }
    __syncthreads();
    if (tid < 64) {
        int bb = tid >> 4, hl2 = tid & 15;
        float ir = xi[0][hl2][bb], hr = xh[0][hl2][bb];
        float iz = xi[1][hl2][bb], hz = xh[1][hl2][bb];
        float in_ = xi[2][hl2][bb], hn = xh[2][hl2][bb];
        float r = fsigmoid(ir + hr);
        float z = fsigmoid(iz + hz);
        float n = ftanh(in_ + r * hn);
        out[(bt * 4 + bb) * 256 + ht * 16 + hl2] =
            (1.f - z) * n + z * ld_s[bb][ht * 16 + hl2];
    }
}

extern "C" void kernel_launch(void* const* d_in, const int* in_sizes, int n_in,
                              void* d_out, int out_size, void* d_ws, size_t ws_size,
                              hipStream_t stream) {
    const float* input  = (const float*)d_in[0];
    const float* memory = (const float*)d_in[1];
    const int*   mask   = (const int*)d_in[2];
    const float* state  = (const float*)d_in[3];
    const float* W_a1   = (const float*)d_in[4];
    const float* w_a2   = (const float*)d_in[5];
    const float* W_gate = (const float*)d_in[6];
    const float* W_ih   = (const float*)d_in[7];
    const float* W_hh   = (const float*)d_in[8];
    const float* b_ih   = (const float*)d_in[9];
    const float* b_hh   = (const float*)d_in[10];
    float* out = (float*)d_out;

    char* ws = (char*)d_ws;
    unsigned short* WmT = (unsigned short*)(ws + 0);        // 131072 B
    float* qs       = (float*)(ws + 131072);                // 65536 B
    float* gated    = (float*)(ws + 196608);                // 131072 B
    float* part_l   = (float*)(ws + 327680);                // 2048 B   [g][b]
    float* part_acc = (float*)(ws + 335872);                // 524288 B [g][b][h]

    prep_qs_kernel<<<320, 256, 0, stream>>>(W_a1, input, state, WmT, qs);

    (void)hipFuncSetAttribute((const void*)attn_kernel,
                              hipFuncAttributeMaxDynamicSharedMemorySize, 70656);
    attn_kernel<<<dim3(B_DIM, NCHG), 512, 70656, stream>>>(
        memory, mask, WmT, qs, w_a2, part_l, part_acc);

    mergegate_kernel<<<64, 512, 0, stream>>>(part_l, part_acc, input, W_gate, gated);
    gru_kernel<<<256, 768, 0, stream>>>(gated, state, W_ih, W_hh, b_ih, b_hh, out);
}